// Round 5
// baseline (95.439 us; speedup 1.0000x reference)
//
#include <hip/hip_runtime.h>
#include <math.h>

// Gabor atom renderer — round 5: shfl-broadcast render, no LDS, no barriers.
//
// out[t] = sum_n a_n * exp(-tc^2/(2 sg^2+1e-8)) * cos(2pi(om tc + 0.5 gm tc^2)+ph)
//          |tc| <= 4 sg,  tc = t/SR - tau_n   (mask dropped: outside pairs
//          contribute <= |a|*2^-11.5, ~1e-3 total vs 3.4e-2 threshold)
//
// vs round 4 (theory: both kernels latency-bound, not issue-bound):
//  - render: 1-wave blocks (64 thr x 8 samples = 512-sample tile). Each lane
//    holds ONE listed atom's params in registers; inner loop broadcasts lane
//    i's params via wave-uniform __shfl (v_readlane -> SGPR). No ds_read
//    (120-cyc), no __syncthreads. 8 independent acc chains per thread.
//  - SEGS=32 -> 4512 blocks = 4.4 waves/SIMD to hide the per-block gather.
//  - prep: ballot scan unrolled x4 (batched loads) -> 16 latency exposures
//    instead of 64.

#define SR         24000.0f
#define TWO_PI     6.2831853071795864769f
#define LOG2E      1.4426950408889634f

#define TS     512   // samples per output tile
#define SPT    8     // samples per thread (64 * 8 = TS)
#define SEGS   32    // list segments per tile => m = ceil(cnt/32) <= 16 <= 64
#define MAXA   512   // max atoms per tile list (mean ~163 at TS=512)

// ---------------------------------------------------------------- fused prep
// blocks [0, ntiles): ballot-compact tile b's atom list (unrolled x4)
// blocks [ntiles, ...): zero out[] via float4 stores
__global__ __launch_bounds__(64) void prep_kernel(
        const float* __restrict__ tau,
        const float* __restrict__ sigma,
        int*   __restrict__ counts,
        int*   __restrict__ lists,
        float* __restrict__ out,
        int N, int T, int ntiles) {
    const int b    = blockIdx.x;
    const int lane = threadIdx.x;

    if (b < ntiles) {
        const float tstart = (float)(b * TS) * (1.0f / SR);
        const float tend   = (float)(b * TS + TS - 1) * (1.0f / SR);
        const float slack  = 2.0f / SR;
        int cnt = 0;
        for (int c = 0; c < N; c += 256) {           // 4 chunks of 64 per iter
            float tu[4], w[4];
            #pragma unroll
            for (int u = 0; u < 4; ++u) {            // batch loads first
                const int ai = c + u * 64 + lane;
                tu[u] = (ai < N) ? tau[ai]   : 1e9f;
                w[u]  = (ai < N) ? (4.0f * sigma[ai] + slack) : 0.0f;
            }
            #pragma unroll
            for (int u = 0; u < 4; ++u) {            // then 4 ballot rounds
                const bool hit = ((tu[u] - w[u]) <= tend) && ((tu[u] + w[u]) >= tstart);
                const unsigned long long mb = __ballot(hit);
                if (hit) {
                    const int pos = cnt + (int)__popcll(mb & ((1ull << lane) - 1ull));
                    if (pos < MAXA) lists[b * MAXA + pos] = c + u * 64 + lane;
                }
                cnt += (int)__popcll(mb);
            }
        }
        if (lane == 0) counts[b] = (cnt < MAXA) ? cnt : MAXA;
    } else {
        const int i4 = (b - ntiles) * 64 + lane;     // T % 4 == 0
        if (i4 * 4 < T) ((float4*)out)[i4] = make_float4(0.f, 0.f, 0.f, 0.f);
    }
}

// ------------------------------------------------------------------- render
__global__ __launch_bounds__(64) void render_kernel(
        const float* __restrict__ amp,
        const float* __restrict__ tau,
        const float* __restrict__ omega,
        const float* __restrict__ sigma,
        const float* __restrict__ phi,
        const float* __restrict__ gamma,
        const int*   __restrict__ counts,
        const int*   __restrict__ lists,
        float*       __restrict__ out,
        int T) {
    const int tile = blockIdx.x;
    const int seg  = blockIdx.y;
    const int lane = threadIdx.x;

    const int cnt = counts[tile];
    const int per = (cnt + SEGS - 1) / SEGS;
    const int a0  = seg * per;
    const int a1  = min(cnt, a0 + per);
    const int m   = a1 - a0;                 // <= ceil(MAXA/SEGS) = 16 <= 64
    if (m <= 0) return;

    // each lane gathers one atom's params into registers (L2-hot, 16KB arrays)
    float pa = 0.f, ptu = 0.f, pom = 0.f, phg = 0.f, pk = 0.f, pph = 0.f;
    if (lane < m) {
        const int idx = lists[tile * MAXA + a0 + lane];
        pa  = amp[idx];
        ptu = tau[idx];
        pom = omega[idx];
        phg = 0.5f * gamma[idx];
        pph = phi[idx] * (1.0f / TWO_PI);
        const float sg = sigma[idx];
        pk  = -LOG2E / (2.0f * sg * sg + 1e-8f);
    }

    const int   s_base = tile * TS;
    const float t0 = (float)(s_base + lane) * (1.0f / SR);
    const float dt = 64.0f * (1.0f / SR);

    float acc[SPT] = {0.f, 0.f, 0.f, 0.f, 0.f, 0.f, 0.f, 0.f};

    for (int i = 0; i < m; ++i) {            // i wave-uniform -> v_readlane
        const float ai_ = __shfl(pa,  i);
        const float tui = __shfl(ptu, i);
        const float omi = __shfl(pom, i);
        const float hgi = __shfl(phg, i);
        const float ki  = __shfl(pk,  i);
        const float phi_= __shfl(pph, i);
        const float tc0 = t0 - tui;
        #pragma unroll
        for (int j = 0; j < SPT; ++j) {
            const float tc  = tc0 + (float)j * dt;
            const float tc2 = tc * tc;
            const float env = exp2f(ki * tc2);                    // v_exp_f32
            const float rev = fmaf(omi, tc, fmaf(hgi, tc2, phi_));
            const float r   = rev - floorf(rev);                  // v_fract
            const float c   = __builtin_amdgcn_cosf(r);           // v_cos_f32
            acc[j] = fmaf(ai_ * env, c, acc[j]);
        }
    }

    #pragma unroll
    for (int j = 0; j < SPT; ++j) {
        const int t_idx = s_base + lane + j * 64;                 // coalesced
        if (t_idx < T) atomicAdd(&out[t_idx], acc[j]);
    }
}

extern "C" void kernel_launch(void* const* d_in, const int* in_sizes, int n_in,
                              void* d_out, int out_size, void* d_ws, size_t ws_size,
                              hipStream_t stream) {
    const float* amp   = (const float*)d_in[0];
    const float* tau   = (const float*)d_in[1];
    const float* omega = (const float*)d_in[2];
    const float* sigma = (const float*)d_in[3];
    const float* phi   = (const float*)d_in[4];
    const float* gamma = (const float*)d_in[5];

    float* out = (float*)d_out;
    const int T = out_size;                 // 72000
    const int N = in_sizes[0];              // 4096
    const int ntiles = (T + TS - 1) / TS;   // 141

    char* ws = (char*)d_ws;
    int* counts = (int*)ws;                                  // ntiles ints
    int* lists  = (int*)(ws + (size_t)ntiles * sizeof(int)); // ntiles*MAXA ints

    const int zblocks = (T / 4 + 63) / 64;
    prep_kernel<<<ntiles + zblocks, 64, 0, stream>>>(tau, sigma, counts, lists,
                                                     out, N, T, ntiles);
    dim3 grid(ntiles, SEGS);
    render_kernel<<<grid, 64, 0, stream>>>(amp, tau, omega, sigma, phi, gamma,
                                           counts, lists, out, T);
}